// Round 1
// baseline (589.044 us; speedup 1.0000x reference)
//
#include <hip/hip_runtime.h>
#include <math.h>

#define NN 50000
#define NE 800000
#define FD 128      // IN == HC == 128
#define NB 64
#define DDIM 32

// ---------------- init: zero degree histogram + pooled accumulators ----------------
__global__ void k_init(int* __restrict__ deg, float* __restrict__ pooled) {
  int i = blockIdx.x * blockDim.x + threadIdx.x;
  if (i < NN) deg[i] = 0;
  if (i < NB * FD) pooled[i] = 0.f;
}

// ---------------- degree histogram over edge destinations ----------------
__global__ void k_hist(const int* __restrict__ dst, int* __restrict__ deg) {
  int e = blockIdx.x * blockDim.x + threadIdx.x;
  if (e < NE) atomicAdd(&deg[dst[e]], 1);
}

// ---------------- single-block exclusive scan -> CSR offsets (+ cursor copy) ----------------
__global__ __launch_bounds__(1024) void k_scan(const int* __restrict__ deg,
                                               int* __restrict__ offs,
                                               int* __restrict__ cursor) {
  __shared__ int sd[1024];
  __shared__ int s_run;
  int t = threadIdx.x;
  if (t == 0) s_run = 0;
  __syncthreads();
  for (int base = 0; base < NN; base += 1024) {
    int i = base + t;
    int v = (i < NN) ? deg[i] : 0;
    sd[t] = v;
    __syncthreads();
    for (int off = 1; off < 1024; off <<= 1) {
      int y = (t >= off) ? sd[t - off] : 0;
      __syncthreads();
      sd[t] += y;
      __syncthreads();
    }
    int run = s_run;
    int excl = run + sd[t] - v;
    if (i < NN) { offs[i] = excl; cursor[i] = excl; }
    int tot = sd[1023];
    __syncthreads();
    if (t == 0) s_run = run + tot;
    __syncthreads();
  }
  if (t == 0) offs[NN] = s_run;   // == NE
}

// ---------------- scatter edge sources into CSR order ----------------
__global__ void k_scatter(const int* __restrict__ src, const int* __restrict__ dst,
                          int* __restrict__ cursor, int* __restrict__ ssrc) {
  int e = blockIdx.x * blockDim.x + threadIdx.x;
  if (e < NE) {
    int p = atomicAdd(&cursor[dst[e]], 1);
    ssrc[p] = src[e];
  }
}

// ---------------- out[r][c] = sum_k in[r][k] * W[c][k] + b[c]  (128x128 W) ----------------
// Block: 32 rows x 128 cols, 256 threads, 4x4 register tile per thread.
// W staged in LDS with XOR swizzle so stride-4-row b128 reads hit the b128 floor.
__global__ __launch_bounds__(256) void k_linear(const float* __restrict__ in,
    const float* __restrict__ W, const float* __restrict__ b,
    float* __restrict__ out, int nrows) {
  __shared__ float wl[FD * FD];    // 64 KB, swizzled
  __shared__ float xs[32 * FD];    // 16 KB
  // stage W (swizzled within each row)
  for (int idx = threadIdx.x; idx < FD * 32; idx += 256) {
    int row = idx >> 5, k4 = idx & 31;
    float4 w = ((const float4*)W)[idx];
    int slot = k4 ^ ((row >> 2) & 7);
    *(float4*)&wl[row * FD + slot * 4] = w;
  }
  // stage x tile
  int rbase = blockIdx.x * 32;
  for (int idx = threadIdx.x; idx < 32 * 32; idx += 256) {
    int row = idx >> 5, k4 = idx & 31;
    int r = rbase + row;
    float4 v = make_float4(0.f, 0.f, 0.f, 0.f);
    if (r < nrows) v = ((const float4*)in)[(size_t)r * 32 + k4];
    *(float4*)&xs[row * FD + k4 * 4] = v;
  }
  __syncthreads();
  int cg = threadIdx.x & 31;   // col group: cols cg*4 .. cg*4+3
  int rg = threadIdx.x >> 5;   // row group: rows rg*4 .. rg*4+3
  float acc[4][4] = {};
  #pragma unroll 4
  for (int k4 = 0; k4 < 32; ++k4) {
    float4 xa[4];
    #pragma unroll
    for (int i = 0; i < 4; ++i)
      xa[i] = *(const float4*)&xs[(rg * 4 + i) * FD + k4 * 4];
    int slot = k4 ^ (cg & 7);
    #pragma unroll
    for (int j = 0; j < 4; ++j) {
      float4 w = *(const float4*)&wl[(cg * 4 + j) * FD + slot * 4];
      #pragma unroll
      for (int i = 0; i < 4; ++i)
        acc[i][j] += xa[i].x * w.x + xa[i].y * w.y + xa[i].z * w.z + xa[i].w * w.w;
    }
  }
  float4 b4 = ((const float4*)b)[cg];
  #pragma unroll
  for (int i = 0; i < 4; ++i) {
    int r = rbase + rg * 4 + i;
    if (r < nrows) {
      float4 o;
      o.x = acc[i][0] + b4.x;
      o.y = acc[i][1] + b4.y;
      o.z = acc[i][2] + b4.z;
      o.w = acc[i][3] + b4.w;
      ((float4*)out)[(size_t)r * 32 + cg] = o;
    }
  }
}

__device__ __forceinline__ float lrelu(float x) { return x > 0.f ? x : 0.2f * x; }

// ---------------- GATv2 edge+softmax+aggregate, node-centric online softmax ----------------
// 32 lanes per node (lane holds channels 4l..4l+3, head = l>>3). CSR in-edges.
__global__ __launch_bounds__(256) void k_gat(const float* __restrict__ xl,
    const float* __restrict__ xr, const int* __restrict__ offs,
    const int* __restrict__ ssrc, const float* __restrict__ att,
    const float* __restrict__ bias, const float* __restrict__ resid,
    float* __restrict__ out) {
  int grp = threadIdx.x >> 5;
  int lane = threadIdx.x & 31;
  int n = blockIdx.x * 8 + grp;
  if (n >= NN) return;
  float4 att4 = ((const float4*)att)[lane];
  float4 xr4 = ((const float4*)xr)[(size_t)n * 32 + lane];
  int e0 = offs[n], e1 = offs[n + 1];
  float m = -1e30f, den = 0.f;
  float4 acc = make_float4(0.f, 0.f, 0.f, 0.f);
  int e = e0;
  for (; e + 1 < e1; e += 2) {
    int s0 = ssrc[e];
    int s1 = ssrc[e + 1];
    float4 v0 = ((const float4*)xl)[(size_t)s0 * 32 + lane];
    float4 v1 = ((const float4*)xl)[(size_t)s1 * 32 + lane];
    float p0 = lrelu(v0.x + xr4.x) * att4.x + lrelu(v0.y + xr4.y) * att4.y +
               lrelu(v0.z + xr4.z) * att4.z + lrelu(v0.w + xr4.w) * att4.w;
    float p1 = lrelu(v1.x + xr4.x) * att4.x + lrelu(v1.y + xr4.y) * att4.y +
               lrelu(v1.z + xr4.z) * att4.z + lrelu(v1.w + xr4.w) * att4.w;
    p0 += __shfl_xor(p0, 1, 64); p0 += __shfl_xor(p0, 2, 64); p0 += __shfl_xor(p0, 4, 64);
    p1 += __shfl_xor(p1, 1, 64); p1 += __shfl_xor(p1, 2, 64); p1 += __shfl_xor(p1, 4, 64);
    float nm = fmaxf(m, fmaxf(p0, p1));
    float sc = __expf(m - nm);
    float w0 = __expf(p0 - nm);
    float w1 = __expf(p1 - nm);
    den = den * sc + w0 + w1;
    acc.x = acc.x * sc + w0 * v0.x + w1 * v1.x;
    acc.y = acc.y * sc + w0 * v0.y + w1 * v1.y;
    acc.z = acc.z * sc + w0 * v0.z + w1 * v1.z;
    acc.w = acc.w * sc + w0 * v0.w + w1 * v1.w;
    m = nm;
  }
  if (e < e1) {
    int s0 = ssrc[e];
    float4 v0 = ((const float4*)xl)[(size_t)s0 * 32 + lane];
    float p0 = lrelu(v0.x + xr4.x) * att4.x + lrelu(v0.y + xr4.y) * att4.y +
               lrelu(v0.z + xr4.z) * att4.z + lrelu(v0.w + xr4.w) * att4.w;
    p0 += __shfl_xor(p0, 1, 64); p0 += __shfl_xor(p0, 2, 64); p0 += __shfl_xor(p0, 4, 64);
    float nm = fmaxf(m, p0);
    float sc = __expf(m - nm);
    float w0 = __expf(p0 - nm);
    den = den * sc + w0;
    acc.x = acc.x * sc + w0 * v0.x;
    acc.y = acc.y * sc + w0 * v0.y;
    acc.z = acc.z * sc + w0 * v0.z;
    acc.w = acc.w * sc + w0 * v0.w;
    m = nm;
  }
  float inv = (den > 0.f) ? 1.f / den : 0.f;
  float4 b4 = ((const float4*)bias)[lane];
  float4 r4 = ((const float4*)resid)[(size_t)n * 32 + lane];
  float4 o;
  o.x = fmaxf(acc.x * inv + b4.x, 0.f) + r4.x;
  o.y = fmaxf(acc.y * inv + b4.y, 0.f) + r4.y;
  o.z = fmaxf(acc.z * inv + b4.z, 0.f) + r4.z;
  o.w = fmaxf(acc.w * inv + b4.w, 0.f) + r4.w;
  ((float4*)out)[(size_t)n * 32 + lane] = o;
}

// ---------------- mean-pool over sorted batch, run-length-compressed atomics ----------------
__global__ __launch_bounds__(256) void k_pool(const float* __restrict__ h,
    const int* __restrict__ batch, float* __restrict__ pooled) {
  int col = threadIdx.x & 127;
  int ro = threadIdx.x >> 7;          // 0..1
  int n0 = blockIdx.x * 128;
  float rs = 0.f;
  int cb = -1;
  for (int i = ro; i < 128; i += 2) {
    int n = n0 + i;
    if (n >= NN) break;
    int bb = batch[n];
    if (bb != cb) {
      if (cb >= 0) atomicAdd(&pooled[cb * FD + col], rs);
      rs = 0.f; cb = bb;
    }
    rs += h[(size_t)n * FD + col];
  }
  if (cb >= 0) atomicAdd(&pooled[cb * FD + col], rs);
}

// ---------------- MLP head: one block per graph ----------------
__global__ __launch_bounds__(128) void k_mlp(const float* __restrict__ pooled,
    const int* __restrict__ batch, const float* __restrict__ domain,
    const float* __restrict__ Wg, const float* __restrict__ bg,
    const float* __restrict__ Wd, const float* __restrict__ bd,
    const float* __restrict__ Wf1, const float* __restrict__ bf1,
    const float* __restrict__ Wf2, const float* __restrict__ bf2,
    const float* __restrict__ Wf3, const float* __restrict__ bf3,
    float* __restrict__ out) {
  __shared__ float z[192];
  __shared__ float z1[128];
  __shared__ float z2[64];
  __shared__ float pm[128];
  __shared__ int cnt;
  int b = blockIdx.x, t = threadIdx.x;
  if (t == 0) {
    int lo = 0, hi = NN;
    while (lo < hi) { int mid = (lo + hi) >> 1; if (batch[mid] < b) lo = mid + 1; else hi = mid; }
    int lb = lo; lo = 0; hi = NN;
    while (lo < hi) { int mid = (lo + hi) >> 1; if (batch[mid] < b + 1) lo = mid + 1; else hi = mid; }
    cnt = lo - lb;
  }
  __syncthreads();
  float invc = 1.f / fmaxf((float)cnt, 1.f);
  pm[t] = pooled[b * FD + t] * invc;
  __syncthreads();
  {
    float a = bg[t];
    for (int k = 0; k < 128; ++k) a += pm[k] * Wg[t * 128 + k];
    z[t] = fmaxf(a, 0.f);
  }
  if (t < 64) {
    float a = bd[t];
    for (int k = 0; k < 32; ++k) a += domain[b * 32 + k] * Wd[t * 32 + k];
    z[128 + t] = fmaxf(a, 0.f);
  }
  __syncthreads();
  {
    float a = bf1[t];
    for (int k = 0; k < 192; ++k) a += z[k] * Wf1[t * 192 + k];
    z1[t] = fmaxf(a, 0.f);
  }
  __syncthreads();
  if (t < 64) {
    float a = bf2[t];
    for (int k = 0; k < 128; ++k) a += z1[k] * Wf2[t * 128 + k];
    z2[t] = fmaxf(a, 0.f);
  }
  __syncthreads();
  if (t < 64) {
    float v = z2[t] * Wf3[t];
    for (int off = 1; off < 64; off <<= 1) v += __shfl_xor(v, off, 64);
    if (t == 0) out[b] = v + bf3[0];
  }
}

extern "C" void kernel_launch(void* const* d_in, const int* in_sizes, int n_in,
                              void* d_out, int out_size, void* d_ws, size_t ws_size,
                              hipStream_t stream) {
  const float* x      = (const float*)d_in[0];
  const float* domain = (const float*)d_in[1];
  const float* Wl1 = (const float*)d_in[2];  const float* bl1 = (const float*)d_in[3];
  const float* Wr1 = (const float*)d_in[4];  const float* br1 = (const float*)d_in[5];
  const float* att1= (const float*)d_in[6];  const float* bias1=(const float*)d_in[7];
  const float* Wl2 = (const float*)d_in[8];  const float* bl2 = (const float*)d_in[9];
  const float* Wr2 = (const float*)d_in[10]; const float* br2 = (const float*)d_in[11];
  const float* att2= (const float*)d_in[12]; const float* bias2=(const float*)d_in[13];
  const float* Wres= (const float*)d_in[14]; const float* bres= (const float*)d_in[15];
  const float* Wd  = (const float*)d_in[16]; const float* bd  = (const float*)d_in[17];
  const float* Wg  = (const float*)d_in[18]; const float* bg  = (const float*)d_in[19];
  const float* Wf1 = (const float*)d_in[20]; const float* bf1 = (const float*)d_in[21];
  const float* Wf2 = (const float*)d_in[22]; const float* bf2 = (const float*)d_in[23];
  const float* Wf3 = (const float*)d_in[24]; const float* bf3 = (const float*)d_in[25];
  const int* ei    = (const int*)d_in[26];
  const int* batch = (const int*)d_in[27];
  const int* esrc = ei;
  const int* edst = ei + NE;
  float* outp = (float*)d_out;

  char* p = (char*)d_ws;
  auto carve = [&](size_t bytes) { char* r = p; p += (bytes + 255) & ~(size_t)255; return r; };
  int* deg      = (int*)carve((size_t)NN * 4);
  int* offs     = (int*)carve((size_t)(NN + 1) * 4);
  int* cursor   = (int*)carve((size_t)NN * 4);
  int* ssrc     = (int*)carve((size_t)NE * 4);
  float* xl     = (float*)carve((size_t)NN * FD * 4);
  float* xr     = (float*)carve((size_t)NN * FD * 4);
  float* res    = (float*)carve((size_t)NN * FD * 4);
  float* h1     = (float*)carve((size_t)NN * FD * 4);
  float* pooled = (float*)carve((size_t)NB * FD * 4);
  float* h2 = res;   // res is dead once h1 exists; alias to save workspace

  dim3 b256(256);
  hipLaunchKernelGGL(k_init, dim3((NN + 255) / 256), b256, 0, stream, deg, pooled);
  hipLaunchKernelGGL(k_hist, dim3((NE + 255) / 256), b256, 0, stream, edst, deg);
  hipLaunchKernelGGL(k_scan, dim3(1), dim3(1024), 0, stream, deg, offs, cursor);
  hipLaunchKernelGGL(k_scatter, dim3((NE + 255) / 256), b256, 0, stream, esrc, edst, cursor, ssrc);

  dim3 ling((NN + 31) / 32);
  hipLaunchKernelGGL(k_linear, ling, b256, 0, stream, x, Wres, bres, res, NN);
  hipLaunchKernelGGL(k_linear, ling, b256, 0, stream, x, Wl1, bl1, xl, NN);
  hipLaunchKernelGGL(k_linear, ling, b256, 0, stream, x, Wr1, br1, xr, NN);
  hipLaunchKernelGGL(k_gat, dim3((NN + 7) / 8), b256, 0, stream, xl, xr, offs, ssrc, att1, bias1, res, h1);
  hipLaunchKernelGGL(k_linear, ling, b256, 0, stream, h1, Wl2, bl2, xl, NN);
  hipLaunchKernelGGL(k_linear, ling, b256, 0, stream, h1, Wr2, br2, xr, NN);
  hipLaunchKernelGGL(k_gat, dim3((NN + 7) / 8), b256, 0, stream, xl, xr, offs, ssrc, att2, bias2, h1, h2);
  hipLaunchKernelGGL(k_pool, dim3((NN + 127) / 128), b256, 0, stream, h2, batch, pooled);
  hipLaunchKernelGGL(k_mlp, dim3(NB), dim3(128), 0, stream, pooled, batch, domain,
                     Wg, bg, Wd, bd, Wf1, bf1, Wf2, bf2, Wf3, bf3, outp);
}

// Round 2
// 499.703 us; speedup vs baseline: 1.1788x; 1.1788x over previous
//
#include <hip/hip_runtime.h>
#include <math.h>

#define NN 50000
#define NE 800000
#define FD 128      // IN == HC == 128
#define NB 64
#define DDIM 32
#define SCAN_BLK 1024
#define NSCAN ((NN + SCAN_BLK - 1) / SCAN_BLK)   // 49

// ---------------- init: zero degree histogram + pooled accumulators ----------------
__global__ void k_init(int* __restrict__ deg, float* __restrict__ pooled) {
  int i = blockIdx.x * blockDim.x + threadIdx.x;
  if (i < NN) deg[i] = 0;
  if (i < NB * FD) pooled[i] = 0.f;
}

// ---------------- degree histogram over edge destinations ----------------
__global__ void k_hist(const int* __restrict__ dst, int* __restrict__ deg) {
  int e = blockIdx.x * blockDim.x + threadIdx.x;
  if (e < NE) atomicAdd(&deg[dst[e]], 1);
}

// ---------------- hierarchical scan, phase 1: per-block exclusive scan + block totals ----
__global__ __launch_bounds__(SCAN_BLK) void k_scan1(const int* __restrict__ deg,
                                                    int* __restrict__ excl,
                                                    int* __restrict__ blocksum) {
  __shared__ int ws[16];
  int t = threadIdx.x;
  int i = blockIdx.x * SCAN_BLK + t;
  int v = (i < NN) ? deg[i] : 0;
  int lane = t & 63, wave = t >> 6;
  int s = v;
  #pragma unroll
  for (int off = 1; off < 64; off <<= 1) {
    int y = __shfl_up(s, off, 64);
    if (lane >= off) s += y;
  }
  if (lane == 63) ws[wave] = s;
  __syncthreads();
  if (t < 16) {
    int x = ws[t];
    #pragma unroll
    for (int off = 1; off < 16; off <<= 1) {
      int y = __shfl_up(x, off, 64);
      if (t >= off) x += y;
    }
    ws[t] = x;
  }
  __syncthreads();
  int incl = s + (wave > 0 ? ws[wave - 1] : 0);
  if (i < NN) excl[i] = incl - v;
  if (t == SCAN_BLK - 1) blocksum[blockIdx.x] = incl;
}

// ---------------- phase 2: exclusive scan of the 49 block totals (one wave) ----------
__global__ void k_scan2(int* __restrict__ blocksum) {
  int t = threadIdx.x;   // 64 threads
  int v = (t < NSCAN) ? blocksum[t] : 0;
  int s = v;
  #pragma unroll
  for (int off = 1; off < 64; off <<= 1) {
    int y = __shfl_up(s, off, 64);
    if (t >= off) s += y;
  }
  if (t < NSCAN) blocksum[t] = s - v;          // exclusive prefix
  if (t == 63) blocksum[NSCAN] = s;            // total (== NE)
}

// ---------------- phase 3: add block prefix, emit offs + cursor ----------
__global__ __launch_bounds__(SCAN_BLK) void k_scan3(const int* __restrict__ excl,
                                                    const int* __restrict__ blocksum,
                                                    int* __restrict__ offs,
                                                    int* __restrict__ cursor) {
  int t = threadIdx.x;
  int i = blockIdx.x * SCAN_BLK + t;
  if (i < NN) {
    int o = excl[i] + blocksum[blockIdx.x];
    offs[i] = o;
    cursor[i] = o;
  }
  if (i == 0) offs[NN] = blocksum[NSCAN];
}

// ---------------- scatter edge sources into CSR order ----------------
__global__ void k_scatter(const int* __restrict__ src, const int* __restrict__ dst,
                          int* __restrict__ cursor, int* __restrict__ ssrc) {
  int e = blockIdx.x * blockDim.x + threadIdx.x;
  if (e < NE) {
    int p = atomicAdd(&cursor[dst[e]], 1);
    ssrc[p] = src[e];
  }
}

// ---------------- out[r][c] = sum_k in[r][k] * W[c][k] + b[c]  (128x128 W) ----------------
__global__ __launch_bounds__(256) void k_linear(const float* __restrict__ in,
    const float* __restrict__ W, const float* __restrict__ b,
    float* __restrict__ out, int nrows) {
  __shared__ float wl[FD * FD];    // 64 KB, swizzled
  __shared__ float xs[32 * FD];    // 16 KB
  for (int idx = threadIdx.x; idx < FD * 32; idx += 256) {
    int row = idx >> 5, k4 = idx & 31;
    float4 w = ((const float4*)W)[idx];
    int slot = k4 ^ ((row >> 2) & 7);
    *(float4*)&wl[row * FD + slot * 4] = w;
  }
  int rbase = blockIdx.x * 32;
  for (int idx = threadIdx.x; idx < 32 * 32; idx += 256) {
    int row = idx >> 5, k4 = idx & 31;
    int r = rbase + row;
    float4 v = make_float4(0.f, 0.f, 0.f, 0.f);
    if (r < nrows) v = ((const float4*)in)[(size_t)r * 32 + k4];
    *(float4*)&xs[row * FD + k4 * 4] = v;
  }
  __syncthreads();
  int cg = threadIdx.x & 31;
  int rg = threadIdx.x >> 5;
  float acc[4][4] = {};
  #pragma unroll 4
  for (int k4 = 0; k4 < 32; ++k4) {
    float4 xa[4];
    #pragma unroll
    for (int i = 0; i < 4; ++i)
      xa[i] = *(const float4*)&xs[(rg * 4 + i) * FD + k4 * 4];
    int slot = k4 ^ (cg & 7);
    #pragma unroll
    for (int j = 0; j < 4; ++j) {
      float4 w = *(const float4*)&wl[(cg * 4 + j) * FD + slot * 4];
      #pragma unroll
      for (int i = 0; i < 4; ++i)
        acc[i][j] += xa[i].x * w.x + xa[i].y * w.y + xa[i].z * w.z + xa[i].w * w.w;
    }
  }
  float4 b4 = ((const float4*)b)[cg];
  #pragma unroll
  for (int i = 0; i < 4; ++i) {
    int r = rbase + rg * 4 + i;
    if (r < nrows) {
      float4 o;
      o.x = acc[i][0] + b4.x;
      o.y = acc[i][1] + b4.y;
      o.z = acc[i][2] + b4.z;
      o.w = acc[i][3] + b4.w;
      ((float4*)out)[(size_t)r * 32 + cg] = o;
    }
  }
}

__device__ __forceinline__ float lrelu(float x) { return x > 0.f ? x : 0.2f * x; }

// ---------------- GATv2 edge+softmax+aggregate, node-centric online softmax ----------------
__global__ __launch_bounds__(256) void k_gat(const float* __restrict__ xl,
    const float* __restrict__ xr, const int* __restrict__ offs,
    const int* __restrict__ ssrc, const float* __restrict__ att,
    const float* __restrict__ bias, const float* __restrict__ resid,
    float* __restrict__ out) {
  int grp = threadIdx.x >> 5;
  int lane = threadIdx.x & 31;
  int n = blockIdx.x * 8 + grp;
  if (n >= NN) return;
  float4 att4 = ((const float4*)att)[lane];
  float4 xr4 = ((const float4*)xr)[(size_t)n * 32 + lane];
  int e0 = offs[n], e1 = offs[n + 1];
  float m = -1e30f, den = 0.f;
  float4 acc = make_float4(0.f, 0.f, 0.f, 0.f);
  int e = e0;
  for (; e + 1 < e1; e += 2) {
    int s0 = ssrc[e];
    int s1 = ssrc[e + 1];
    float4 v0 = ((const float4*)xl)[(size_t)s0 * 32 + lane];
    float4 v1 = ((const float4*)xl)[(size_t)s1 * 32 + lane];
    float p0 = lrelu(v0.x + xr4.x) * att4.x + lrelu(v0.y + xr4.y) * att4.y +
               lrelu(v0.z + xr4.z) * att4.z + lrelu(v0.w + xr4.w) * att4.w;
    float p1 = lrelu(v1.x + xr4.x) * att4.x + lrelu(v1.y + xr4.y) * att4.y +
               lrelu(v1.z + xr4.z) * att4.z + lrelu(v1.w + xr4.w) * att4.w;
    p0 += __shfl_xor(p0, 1, 64); p0 += __shfl_xor(p0, 2, 64); p0 += __shfl_xor(p0, 4, 64);
    p1 += __shfl_xor(p1, 1, 64); p1 += __shfl_xor(p1, 2, 64); p1 += __shfl_xor(p1, 4, 64);
    float nm = fmaxf(m, fmaxf(p0, p1));
    float sc = __expf(m - nm);
    float w0 = __expf(p0 - nm);
    float w1 = __expf(p1 - nm);
    den = den * sc + w0 + w1;
    acc.x = acc.x * sc + w0 * v0.x + w1 * v1.x;
    acc.y = acc.y * sc + w0 * v0.y + w1 * v1.y;
    acc.z = acc.z * sc + w0 * v0.z + w1 * v1.z;
    acc.w = acc.w * sc + w0 * v0.w + w1 * v1.w;
    m = nm;
  }
  if (e < e1) {
    int s0 = ssrc[e];
    float4 v0 = ((const float4*)xl)[(size_t)s0 * 32 + lane];
    float p0 = lrelu(v0.x + xr4.x) * att4.x + lrelu(v0.y + xr4.y) * att4.y +
               lrelu(v0.z + xr4.z) * att4.z + lrelu(v0.w + xr4.w) * att4.w;
    p0 += __shfl_xor(p0, 1, 64); p0 += __shfl_xor(p0, 2, 64); p0 += __shfl_xor(p0, 4, 64);
    float nm = fmaxf(m, p0);
    float sc = __expf(m - nm);
    float w0 = __expf(p0 - nm);
    den = den * sc + w0;
    acc.x = acc.x * sc + w0 * v0.x;
    acc.y = acc.y * sc + w0 * v0.y;
    acc.z = acc.z * sc + w0 * v0.z;
    acc.w = acc.w * sc + w0 * v0.w;
    m = nm;
  }
  float inv = (den > 0.f) ? 1.f / den : 0.f;
  float4 b4 = ((const float4*)bias)[lane];
  float4 r4 = ((const float4*)resid)[(size_t)n * 32 + lane];
  float4 o;
  o.x = fmaxf(acc.x * inv + b4.x, 0.f) + r4.x;
  o.y = fmaxf(acc.y * inv + b4.y, 0.f) + r4.y;
  o.z = fmaxf(acc.z * inv + b4.z, 0.f) + r4.z;
  o.w = fmaxf(acc.w * inv + b4.w, 0.f) + r4.w;
  ((float4*)out)[(size_t)n * 32 + lane] = o;
}

// ---------------- mean-pool over sorted batch, run-length-compressed atomics ----------------
__global__ __launch_bounds__(256) void k_pool(const float* __restrict__ h,
    const int* __restrict__ batch, float* __restrict__ pooled) {
  int col = threadIdx.x & 127;
  int ro = threadIdx.x >> 7;
  int n0 = blockIdx.x * 128;
  float rs = 0.f;
  int cb = -1;
  for (int i = ro; i < 128; i += 2) {
    int n = n0 + i;
    if (n >= NN) break;
    int bb = batch[n];
    if (bb != cb) {
      if (cb >= 0) atomicAdd(&pooled[cb * FD + col], rs);
      rs = 0.f; cb = bb;
    }
    rs += h[(size_t)n * FD + col];
  }
  if (cb >= 0) atomicAdd(&pooled[cb * FD + col], rs);
}

// ---------------- MLP head: one block per graph ----------------
__global__ __launch_bounds__(128) void k_mlp(const float* __restrict__ pooled,
    const int* __restrict__ batch, const float* __restrict__ domain,
    const float* __restrict__ Wg, const float* __restrict__ bg,
    const float* __restrict__ Wd, const float* __restrict__ bd,
    const float* __restrict__ Wf1, const float* __restrict__ bf1,
    const float* __restrict__ Wf2, const float* __restrict__ bf2,
    const float* __restrict__ Wf3, const float* __restrict__ bf3,
    float* __restrict__ out) {
  __shared__ float z[192];
  __shared__ float z1[128];
  __shared__ float z2[64];
  __shared__ float pm[128];
  __shared__ int cnt;
  int b = blockIdx.x, t = threadIdx.x;
  if (t == 0) {
    int lo = 0, hi = NN;
    while (lo < hi) { int mid = (lo + hi) >> 1; if (batch[mid] < b) lo = mid + 1; else hi = mid; }
    int lb = lo; lo = 0; hi = NN;
    while (lo < hi) { int mid = (lo + hi) >> 1; if (batch[mid] < b + 1) lo = mid + 1; else hi = mid; }
    cnt = lo - lb;
  }
  __syncthreads();
  float invc = 1.f / fmaxf((float)cnt, 1.f);
  pm[t] = pooled[b * FD + t] * invc;
  __syncthreads();
  {
    float a = bg[t];
    for (int k = 0; k < 128; ++k) a += pm[k] * Wg[t * 128 + k];
    z[t] = fmaxf(a, 0.f);
  }
  if (t < 64) {
    float a = bd[t];
    for (int k = 0; k < 32; ++k) a += domain[b * 32 + k] * Wd[t * 32 + k];
    z[128 + t] = fmaxf(a, 0.f);
  }
  __syncthreads();
  {
    float a = bf1[t];
    for (int k = 0; k < 192; ++k) a += z[k] * Wf1[t * 192 + k];
    z1[t] = fmaxf(a, 0.f);
  }
  __syncthreads();
  if (t < 64) {
    float a = bf2[t];
    for (int k = 0; k < 128; ++k) a += z1[k] * Wf2[t * 128 + k];
    z2[t] = fmaxf(a, 0.f);
  }
  __syncthreads();
  if (t < 64) {
    float v = z2[t] * Wf3[t];
    for (int off = 1; off < 64; off <<= 1) v += __shfl_xor(v, off, 64);
    if (t == 0) out[b] = v + bf3[0];
  }
}

extern "C" void kernel_launch(void* const* d_in, const int* in_sizes, int n_in,
                              void* d_out, int out_size, void* d_ws, size_t ws_size,
                              hipStream_t stream) {
  const float* x      = (const float*)d_in[0];
  const float* domain = (const float*)d_in[1];
  const float* Wl1 = (const float*)d_in[2];  const float* bl1 = (const float*)d_in[3];
  const float* Wr1 = (const float*)d_in[4];  const float* br1 = (const float*)d_in[5];
  const float* att1= (const float*)d_in[6];  const float* bias1=(const float*)d_in[7];
  const float* Wl2 = (const float*)d_in[8];  const float* bl2 = (const float*)d_in[9];
  const float* Wr2 = (const float*)d_in[10]; const float* br2 = (const float*)d_in[11];
  const float* att2= (const float*)d_in[12]; const float* bias2=(const float*)d_in[13];
  const float* Wres= (const float*)d_in[14]; const float* bres= (const float*)d_in[15];
  const float* Wd  = (const float*)d_in[16]; const float* bd  = (const float*)d_in[17];
  const float* Wg  = (const float*)d_in[18]; const float* bg  = (const float*)d_in[19];
  const float* Wf1 = (const float*)d_in[20]; const float* bf1 = (const float*)d_in[21];
  const float* Wf2 = (const float*)d_in[22]; const float* bf2 = (const float*)d_in[23];
  const float* Wf3 = (const float*)d_in[24]; const float* bf3 = (const float*)d_in[25];
  const int* ei    = (const int*)d_in[26];
  const int* batch = (const int*)d_in[27];
  const int* esrc = ei;
  const int* edst = ei + NE;
  float* outp = (float*)d_out;

  char* p = (char*)d_ws;
  auto carve = [&](size_t bytes) { char* r = p; p += (bytes + 255) & ~(size_t)255; return r; };
  int* deg      = (int*)carve((size_t)NN * 4);
  int* offs     = (int*)carve((size_t)(NN + 1) * 4);
  int* cursor   = (int*)carve((size_t)NN * 4);
  int* ssrc     = (int*)carve((size_t)NE * 4);
  int* excl     = (int*)carve((size_t)NN * 4);
  int* blocksum = (int*)carve((size_t)(NSCAN + 1) * 4);
  float* xl     = (float*)carve((size_t)NN * FD * 4);
  float* xr     = (float*)carve((size_t)NN * FD * 4);
  float* res    = (float*)carve((size_t)NN * FD * 4);
  float* h1     = (float*)carve((size_t)NN * FD * 4);
  float* pooled = (float*)carve((size_t)NB * FD * 4);
  float* h2 = res;   // res dead after first GAT; alias

  dim3 b256(256);
  hipLaunchKernelGGL(k_init, dim3((NN + 255) / 256), b256, 0, stream, deg, pooled);
  hipLaunchKernelGGL(k_hist, dim3((NE + 255) / 256), b256, 0, stream, edst, deg);
  hipLaunchKernelGGL(k_scan1, dim3(NSCAN), dim3(SCAN_BLK), 0, stream, deg, excl, blocksum);
  hipLaunchKernelGGL(k_scan2, dim3(1), dim3(64), 0, stream, blocksum);
  hipLaunchKernelGGL(k_scan3, dim3(NSCAN), dim3(SCAN_BLK), 0, stream, excl, blocksum, offs, cursor);
  hipLaunchKernelGGL(k_scatter, dim3((NE + 255) / 256), b256, 0, stream, esrc, edst, cursor, ssrc);

  dim3 ling((NN + 31) / 32);
  hipLaunchKernelGGL(k_linear, ling, b256, 0, stream, x, Wres, bres, res, NN);
  hipLaunchKernelGGL(k_linear, ling, b256, 0, stream, x, Wl1, bl1, xl, NN);
  hipLaunchKernelGGL(k_linear, ling, b256, 0, stream, x, Wr1, br1, xr, NN);
  hipLaunchKernelGGL(k_gat, dim3((NN + 7) / 8), b256, 0, stream, xl, xr, offs, ssrc, att1, bias1, res, h1);
  hipLaunchKernelGGL(k_linear, ling, b256, 0, stream, h1, Wl2, bl2, xl, NN);
  hipLaunchKernelGGL(k_linear, ling, b256, 0, stream, h1, Wr2, br2, xr, NN);
  hipLaunchKernelGGL(k_gat, dim3((NN + 7) / 8), b256, 0, stream, xl, xr, offs, ssrc, att2, bias2, h1, h2);
  hipLaunchKernelGGL(k_pool, dim3((NN + 127) / 128), b256, 0, stream, h2, batch, pooled);
  hipLaunchKernelGGL(k_mlp, dim3(NB), dim3(128), 0, stream, pooled, batch, domain,
                     Wg, bg, Wd, bd, Wf1, bf1, Wf2, bf2, Wf3, bf3, outp);
}

// Round 3
// 367.991 us; speedup vs baseline: 1.6007x; 1.3579x over previous
//
#include <hip/hip_runtime.h>
#include <math.h>

#define NN 50000
#define NE 800000
#define FD 128      // IN == HC == 128
#define NB 64
#define DDIM 32
#define SCAN_BLK 1024
#define NSCAN ((NN + SCAN_BLK - 1) / SCAN_BLK)   // 49

typedef __attribute__((ext_vector_type(8))) short short8v;
typedef __attribute__((ext_vector_type(4))) float f32x4;

// ---------------- init: zero degree histogram + pooled accumulators ----------------
__global__ void k_init(int* __restrict__ deg, float* __restrict__ pooled) {
  int i = blockIdx.x * blockDim.x + threadIdx.x;
  if (i < NN) deg[i] = 0;
  if (i < NB * FD) pooled[i] = 0.f;
}

// ---------------- degree histogram over edge destinations ----------------
__global__ void k_hist(const int* __restrict__ dst, int* __restrict__ deg) {
  int e = blockIdx.x * blockDim.x + threadIdx.x;
  if (e < NE) atomicAdd(&deg[dst[e]], 1);
}

// ---------------- hierarchical scan ----------------
__global__ __launch_bounds__(SCAN_BLK) void k_scan1(const int* __restrict__ deg,
                                                    int* __restrict__ excl,
                                                    int* __restrict__ blocksum) {
  __shared__ int ws[16];
  int t = threadIdx.x;
  int i = blockIdx.x * SCAN_BLK + t;
  int v = (i < NN) ? deg[i] : 0;
  int lane = t & 63, wave = t >> 6;
  int s = v;
  #pragma unroll
  for (int off = 1; off < 64; off <<= 1) {
    int y = __shfl_up(s, off, 64);
    if (lane >= off) s += y;
  }
  if (lane == 63) ws[wave] = s;
  __syncthreads();
  if (t < 16) {
    int x = ws[t];
    #pragma unroll
    for (int off = 1; off < 16; off <<= 1) {
      int y = __shfl_up(x, off, 64);
      if (t >= off) x += y;
    }
    ws[t] = x;
  }
  __syncthreads();
  int incl = s + (wave > 0 ? ws[wave - 1] : 0);
  if (i < NN) excl[i] = incl - v;
  if (t == SCAN_BLK - 1) blocksum[blockIdx.x] = incl;
}

__global__ void k_scan2(int* __restrict__ blocksum) {
  int t = threadIdx.x;   // 64 threads
  int v = (t < NSCAN) ? blocksum[t] : 0;
  int s = v;
  #pragma unroll
  for (int off = 1; off < 64; off <<= 1) {
    int y = __shfl_up(s, off, 64);
    if (t >= off) s += y;
  }
  if (t < NSCAN) blocksum[t] = s - v;
  if (t == 63) blocksum[NSCAN] = s;
}

__global__ __launch_bounds__(SCAN_BLK) void k_scan3(const int* __restrict__ excl,
                                                    const int* __restrict__ blocksum,
                                                    int* __restrict__ offs,
                                                    int* __restrict__ cursor) {
  int t = threadIdx.x;
  int i = blockIdx.x * SCAN_BLK + t;
  if (i < NN) {
    int o = excl[i] + blocksum[blockIdx.x];
    offs[i] = o;
    cursor[i] = o;
  }
  if (i == 0) offs[NN] = blocksum[NSCAN];
}

// ---------------- scatter edge sources into CSR order ----------------
__global__ void k_scatter(const int* __restrict__ src, const int* __restrict__ dst,
                          int* __restrict__ cursor, int* __restrict__ ssrc) {
  int e = blockIdx.x * blockDim.x + threadIdx.x;
  if (e < NE) {
    int p = atomicAdd(&cursor[dst[e]], 1);
    ssrc[p] = src[e];
  }
}

// ---------------- bf16 hi/lo split helpers ----------------
__device__ __forceinline__ unsigned short f2bf(float f) {
  unsigned u = __float_as_uint(f);
  u += 0x7fffu + ((u >> 16) & 1);          // RNE
  return (unsigned short)(u >> 16);
}
__device__ __forceinline__ float bfh2f(unsigned short h) {
  return __uint_as_float(((unsigned)h) << 16);
}

// ---------------- MFMA linear: out[r][c] = sum_k in[r][k]*W[c][k] + b[c] ------------
// Block tile M=64 x N=128, K staged in two 64-halves. 4 waves (2x2), wave tile 32x64.
// bf16 hi/lo split, 3 MFMA per product group, fp32 accumulate. LDS 48 KB.
__global__ __launch_bounds__(256) void k_linmfma(const float* __restrict__ in,
    const float* __restrict__ W, const float* __restrict__ bias,
    float* __restrict__ out, int nrows) {
  __shared__ unsigned short s_ah[64 * 64];   // 8 KB
  __shared__ unsigned short s_al[64 * 64];   // 8 KB
  __shared__ unsigned short s_wh[128 * 64];  // 16 KB
  __shared__ unsigned short s_wl[128 * 64];  // 16 KB
  const int tid = threadIdx.x;
  const int lane = tid & 63;
  const int wv = tid >> 6;
  const int wr = wv >> 1, wc = wv & 1;
  const int m0 = wr * 32, n0 = wc * 64;
  const int rbase = blockIdx.x * 64;
  const int g = lane >> 4;       // quarter-wave group (k-slice)
  const int lr = lane & 15;

  f32x4 acc[2][4];
  #pragma unroll
  for (int mt = 0; mt < 2; ++mt)
    #pragma unroll
    for (int nt = 0; nt < 4; ++nt)
      acc[mt][nt] = (f32x4){0.f, 0.f, 0.f, 0.f};

  float bv[4];
  #pragma unroll
  for (int nt = 0; nt < 4; ++nt) bv[nt] = bias[n0 + nt * 16 + lr];

  for (int kh = 0; kh < 2; ++kh) {
    if (kh) __syncthreads();   // previous compute done before restage
    // stage A half: 64 rows x 8 slots (8 bf16 per slot)
    #pragma unroll
    for (int it = 0; it < 2; ++it) {
      int c = it * 256 + tid;
      int row = c >> 3, slot = c & 7;
      int rg = rbase + row;
      float f[8];
      if (rg < nrows) {
        float4 a0 = *(const float4*)&in[(size_t)rg * 128 + kh * 64 + slot * 8];
        float4 a1 = *(const float4*)&in[(size_t)rg * 128 + kh * 64 + slot * 8 + 4];
        f[0] = a0.x; f[1] = a0.y; f[2] = a0.z; f[3] = a0.w;
        f[4] = a1.x; f[5] = a1.y; f[6] = a1.z; f[7] = a1.w;
      } else {
        #pragma unroll
        for (int j = 0; j < 8; ++j) f[j] = 0.f;
      }
      short8v hi, lo;
      #pragma unroll
      for (int j = 0; j < 8; ++j) {
        unsigned short h = f2bf(f[j]);
        hi[j] = (short)h;
        lo[j] = (short)f2bf(f[j] - bfh2f(h));
      }
      int idx = row * 64 + 8 * (slot ^ (row & 7));
      *(short8v*)&s_ah[idx] = hi;
      *(short8v*)&s_al[idx] = lo;
    }
    // stage W half: 128 rows (out cols) x 8 slots
    #pragma unroll
    for (int it = 0; it < 4; ++it) {
      int c = it * 256 + tid;
      int row = c >> 3, slot = c & 7;
      float4 a0 = *(const float4*)&W[(size_t)row * 128 + kh * 64 + slot * 8];
      float4 a1 = *(const float4*)&W[(size_t)row * 128 + kh * 64 + slot * 8 + 4];
      float f[8] = {a0.x, a0.y, a0.z, a0.w, a1.x, a1.y, a1.z, a1.w};
      short8v hi, lo;
      #pragma unroll
      for (int j = 0; j < 8; ++j) {
        unsigned short h = f2bf(f[j]);
        hi[j] = (short)h;
        lo[j] = (short)f2bf(f[j] - bfh2f(h));
      }
      int idx = row * 64 + 8 * (slot ^ (row & 7));
      *(short8v*)&s_wh[idx] = hi;
      *(short8v*)&s_wl[idx] = lo;
    }
    __syncthreads();
    #pragma unroll
    for (int ks = 0; ks < 2; ++ks) {
      short8v ah[2], al[2];
      #pragma unroll
      for (int mt = 0; mt < 2; ++mt) {
        int row = m0 + mt * 16 + lr;
        int idx = row * 64 + 8 * ((ks * 4 + g) ^ (row & 7));
        ah[mt] = *(const short8v*)&s_ah[idx];
        al[mt] = *(const short8v*)&s_al[idx];
      }
      #pragma unroll
      for (int nt = 0; nt < 4; ++nt) {
        int row = n0 + nt * 16 + lr;
        int idx = row * 64 + 8 * ((ks * 4 + g) ^ (row & 7));
        short8v bh = *(const short8v*)&s_wh[idx];
        short8v bl = *(const short8v*)&s_wl[idx];
        #pragma unroll
        for (int mt = 0; mt < 2; ++mt) {
          acc[mt][nt] = __builtin_amdgcn_mfma_f32_16x16x32_bf16(ah[mt], bh, acc[mt][nt], 0, 0, 0);
          acc[mt][nt] = __builtin_amdgcn_mfma_f32_16x16x32_bf16(ah[mt], bl, acc[mt][nt], 0, 0, 0);
          acc[mt][nt] = __builtin_amdgcn_mfma_f32_16x16x32_bf16(al[mt], bh, acc[mt][nt], 0, 0, 0);
        }
      }
    }
  }
  // store: D row = 4*g + i, col = lane&15 within each 16x16 tile
  #pragma unroll
  for (int mt = 0; mt < 2; ++mt)
    #pragma unroll
    for (int nt = 0; nt < 4; ++nt)
      #pragma unroll
      for (int i = 0; i < 4; ++i) {
        int r = rbase + m0 + mt * 16 + 4 * g + i;
        if (r < nrows)
          out[(size_t)r * 128 + n0 + nt * 16 + lr] = acc[mt][nt][i] + bv[nt];
      }
}

__device__ __forceinline__ float lrelu(float x) { return x > 0.f ? x : 0.2f * x; }

// ---------------- GATv2 edge+softmax+aggregate, node-centric online softmax ----------------
// 32 lanes per node; 4-edge unroll for memory-level parallelism.
__global__ __launch_bounds__(256) void k_gat(const float* __restrict__ xl,
    const float* __restrict__ xr, const int* __restrict__ offs,
    const int* __restrict__ ssrc, const float* __restrict__ att,
    const float* __restrict__ bias, const float* __restrict__ resid,
    float* __restrict__ out) {
  int grp = threadIdx.x >> 5;
  int lane = threadIdx.x & 31;
  int n = blockIdx.x * 8 + grp;
  if (n >= NN) return;
  float4 att4 = ((const float4*)att)[lane];
  float4 xr4 = ((const float4*)xr)[(size_t)n * 32 + lane];
  int e0 = offs[n], e1 = offs[n + 1];
  float m = -1e30f, den = 0.f;
  float4 acc = make_float4(0.f, 0.f, 0.f, 0.f);
  int e = e0;
  for (; e + 3 < e1; e += 4) {
    int s0 = ssrc[e], s1 = ssrc[e + 1], s2 = ssrc[e + 2], s3 = ssrc[e + 3];
    float4 v0 = ((const float4*)xl)[(size_t)s0 * 32 + lane];
    float4 v1 = ((const float4*)xl)[(size_t)s1 * 32 + lane];
    float4 v2 = ((const float4*)xl)[(size_t)s2 * 32 + lane];
    float4 v3 = ((const float4*)xl)[(size_t)s3 * 32 + lane];
    float p0 = lrelu(v0.x + xr4.x) * att4.x + lrelu(v0.y + xr4.y) * att4.y +
               lrelu(v0.z + xr4.z) * att4.z + lrelu(v0.w + xr4.w) * att4.w;
    float p1 = lrelu(v1.x + xr4.x) * att4.x + lrelu(v1.y + xr4.y) * att4.y +
               lrelu(v1.z + xr4.z) * att4.z + lrelu(v1.w + xr4.w) * att4.w;
    float p2 = lrelu(v2.x + xr4.x) * att4.x + lrelu(v2.y + xr4.y) * att4.y +
               lrelu(v2.z + xr4.z) * att4.z + lrelu(v2.w + xr4.w) * att4.w;
    float p3 = lrelu(v3.x + xr4.x) * att4.x + lrelu(v3.y + xr4.y) * att4.y +
               lrelu(v3.z + xr4.z) * att4.z + lrelu(v3.w + xr4.w) * att4.w;
    p0 += __shfl_xor(p0, 1, 64); p0 += __shfl_xor(p0, 2, 64); p0 += __shfl_xor(p0, 4, 64);
    p1 += __shfl_xor(p1, 1, 64); p1 += __shfl_xor(p1, 2, 64); p1 += __shfl_xor(p1, 4, 64);
    p2 += __shfl_xor(p2, 1, 64); p2 += __shfl_xor(p2, 2, 64); p2 += __shfl_xor(p2, 4, 64);
    p3 += __shfl_xor(p3, 1, 64); p3 += __shfl_xor(p3, 2, 64); p3 += __shfl_xor(p3, 4, 64);
    float nm = fmaxf(fmaxf(m, fmaxf(p0, p1)), fmaxf(p2, p3));
    float sc = __expf(m - nm);
    float w0 = __expf(p0 - nm), w1 = __expf(p1 - nm);
    float w2 = __expf(p2 - nm), w3 = __expf(p3 - nm);
    den = den * sc + w0 + w1 + w2 + w3;
    acc.x = acc.x * sc + w0 * v0.x + w1 * v1.x + w2 * v2.x + w3 * v3.x;
    acc.y = acc.y * sc + w0 * v0.y + w1 * v1.y + w2 * v2.y + w3 * v3.y;
    acc.z = acc.z * sc + w0 * v0.z + w1 * v1.z + w2 * v2.z + w3 * v3.z;
    acc.w = acc.w * sc + w0 * v0.w + w1 * v1.w + w2 * v2.w + w3 * v3.w;
    m = nm;
  }
  for (; e < e1; ++e) {
    int s0 = ssrc[e];
    float4 v0 = ((const float4*)xl)[(size_t)s0 * 32 + lane];
    float p0 = lrelu(v0.x + xr4.x) * att4.x + lrelu(v0.y + xr4.y) * att4.y +
               lrelu(v0.z + xr4.z) * att4.z + lrelu(v0.w + xr4.w) * att4.w;
    p0 += __shfl_xor(p0, 1, 64); p0 += __shfl_xor(p0, 2, 64); p0 += __shfl_xor(p0, 4, 64);
    float nm = fmaxf(m, p0);
    float sc = __expf(m - nm);
    float w0 = __expf(p0 - nm);
    den = den * sc + w0;
    acc.x = acc.x * sc + w0 * v0.x;
    acc.y = acc.y * sc + w0 * v0.y;
    acc.z = acc.z * sc + w0 * v0.z;
    acc.w = acc.w * sc + w0 * v0.w;
    m = nm;
  }
  float inv = (den > 0.f) ? 1.f / den : 0.f;
  float4 b4 = ((const float4*)bias)[lane];
  float4 r4 = ((const float4*)resid)[(size_t)n * 32 + lane];
  float4 o;
  o.x = fmaxf(acc.x * inv + b4.x, 0.f) + r4.x;
  o.y = fmaxf(acc.y * inv + b4.y, 0.f) + r4.y;
  o.z = fmaxf(acc.z * inv + b4.z, 0.f) + r4.z;
  o.w = fmaxf(acc.w * inv + b4.w, 0.f) + r4.w;
  ((float4*)out)[(size_t)n * 32 + lane] = o;
}

// ---------------- mean-pool over sorted batch, run-length-compressed atomics ----------------
__global__ __launch_bounds__(256) void k_pool(const float* __restrict__ h,
    const int* __restrict__ batch, float* __restrict__ pooled) {
  int col = threadIdx.x & 127;
  int ro = threadIdx.x >> 7;
  int n0 = blockIdx.x * 128;
  float rs = 0.f;
  int cb = -1;
  for (int i = ro; i < 128; i += 2) {
    int n = n0 + i;
    if (n >= NN) break;
    int bb = batch[n];
    if (bb != cb) {
      if (cb >= 0) atomicAdd(&pooled[cb * FD + col], rs);
      rs = 0.f; cb = bb;
    }
    rs += h[(size_t)n * FD + col];
  }
  if (cb >= 0) atomicAdd(&pooled[cb * FD + col], rs);
}

// ---------------- MLP head: one block per graph ----------------
__global__ __launch_bounds__(128) void k_mlp(const float* __restrict__ pooled,
    const int* __restrict__ batch, const float* __restrict__ domain,
    const float* __restrict__ Wg, const float* __restrict__ bg,
    const float* __restrict__ Wd, const float* __restrict__ bd,
    const float* __restrict__ Wf1, const float* __restrict__ bf1,
    const float* __restrict__ Wf2, const float* __restrict__ bf2,
    const float* __restrict__ Wf3, const float* __restrict__ bf3,
    float* __restrict__ out) {
  __shared__ float z[192];
  __shared__ float z1[128];
  __shared__ float z2[64];
  __shared__ float pm[128];
  __shared__ int cnt;
  int b = blockIdx.x, t = threadIdx.x;
  if (t == 0) {
    int lo = 0, hi = NN;
    while (lo < hi) { int mid = (lo + hi) >> 1; if (batch[mid] < b) lo = mid + 1; else hi = mid; }
    int lb = lo; lo = 0; hi = NN;
    while (lo < hi) { int mid = (lo + hi) >> 1; if (batch[mid] < b + 1) lo = mid + 1; else hi = mid; }
    cnt = lo - lb;
  }
  __syncthreads();
  float invc = 1.f / fmaxf((float)cnt, 1.f);
  pm[t] = pooled[b * FD + t] * invc;
  __syncthreads();
  {
    float a = bg[t];
    for (int k = 0; k < 128; ++k) a += pm[k] * Wg[t * 128 + k];
    z[t] = fmaxf(a, 0.f);
  }
  if (t < 64) {
    float a = bd[t];
    for (int k = 0; k < 32; ++k) a += domain[b * 32 + k] * Wd[t * 32 + k];
    z[128 + t] = fmaxf(a, 0.f);
  }
  __syncthreads();
  {
    float a = bf1[t];
    for (int k = 0; k < 192; ++k) a += z[k] * Wf1[t * 192 + k];
    z1[t] = fmaxf(a, 0.f);
  }
  __syncthreads();
  if (t < 64) {
    float a = bf2[t];
    for (int k = 0; k < 128; ++k) a += z1[k] * Wf2[t * 128 + k];
    z2[t] = fmaxf(a, 0.f);
  }
  __syncthreads();
  if (t < 64) {
    float v = z2[t] * Wf3[t];
    for (int off = 1; off < 64; off <<= 1) v += __shfl_xor(v, off, 64);
    if (t == 0) out[b] = v + bf3[0];
  }
}

extern "C" void kernel_launch(void* const* d_in, const int* in_sizes, int n_in,
                              void* d_out, int out_size, void* d_ws, size_t ws_size,
                              hipStream_t stream) {
  const float* x      = (const float*)d_in[0];
  const float* domain = (const float*)d_in[1];
  const float* Wl1 = (const float*)d_in[2];  const float* bl1 = (const float*)d_in[3];
  const float* Wr1 = (const float*)d_in[4];  const float* br1 = (const float*)d_in[5];
  const float* att1= (const float*)d_in[6];  const float* bias1=(const float*)d_in[7];
  const float* Wl2 = (const float*)d_in[8];  const float* bl2 = (const float*)d_in[9];
  const float* Wr2 = (const float*)d_in[10]; const float* br2 = (const float*)d_in[11];
  const float* att2= (const float*)d_in[12]; const float* bias2=(const float*)d_in[13];
  const float* Wres= (const float*)d_in[14]; const float* bres= (const float*)d_in[15];
  const float* Wd  = (const float*)d_in[16]; const float* bd  = (const float*)d_in[17];
  const float* Wg  = (const float*)d_in[18]; const float* bg  = (const float*)d_in[19];
  const float* Wf1 = (const float*)d_in[20]; const float* bf1 = (const float*)d_in[21];
  const float* Wf2 = (const float*)d_in[22]; const float* bf2 = (const float*)d_in[23];
  const float* Wf3 = (const float*)d_in[24]; const float* bf3 = (const float*)d_in[25];
  const int* ei    = (const int*)d_in[26];
  const int* batch = (const int*)d_in[27];
  const int* esrc = ei;
  const int* edst = ei + NE;
  float* outp = (float*)d_out;

  char* p = (char*)d_ws;
  auto carve = [&](size_t bytes) { char* r = p; p += (bytes + 255) & ~(size_t)255; return r; };
  int* deg      = (int*)carve((size_t)NN * 4);
  int* offs     = (int*)carve((size_t)(NN + 1) * 4);
  int* cursor   = (int*)carve((size_t)NN * 4);
  int* ssrc     = (int*)carve((size_t)NE * 4);
  int* excl     = (int*)carve((size_t)NN * 4);
  int* blocksum = (int*)carve((size_t)(NSCAN + 1) * 4);
  float* xl     = (float*)carve((size_t)NN * FD * 4);
  float* xr     = (float*)carve((size_t)NN * FD * 4);
  float* res    = (float*)carve((size_t)NN * FD * 4);
  float* h1     = (float*)carve((size_t)NN * FD * 4);
  float* pooled = (float*)carve((size_t)NB * FD * 4);
  float* h2 = res;   // res dead after first GAT; alias

  dim3 b256(256);
  hipLaunchKernelGGL(k_init, dim3((NN + 255) / 256), b256, 0, stream, deg, pooled);
  hipLaunchKernelGGL(k_hist, dim3((NE + 255) / 256), b256, 0, stream, edst, deg);
  hipLaunchKernelGGL(k_scan1, dim3(NSCAN), dim3(SCAN_BLK), 0, stream, deg, excl, blocksum);
  hipLaunchKernelGGL(k_scan2, dim3(1), dim3(64), 0, stream, blocksum);
  hipLaunchKernelGGL(k_scan3, dim3(NSCAN), dim3(SCAN_BLK), 0, stream, excl, blocksum, offs, cursor);
  hipLaunchKernelGGL(k_scatter, dim3((NE + 255) / 256), b256, 0, stream, esrc, edst, cursor, ssrc);

  dim3 ling((NN + 63) / 64);
  hipLaunchKernelGGL(k_linmfma, ling, b256, 0, stream, x, Wres, bres, res, NN);
  hipLaunchKernelGGL(k_linmfma, ling, b256, 0, stream, x, Wl1, bl1, xl, NN);
  hipLaunchKernelGGL(k_linmfma, ling, b256, 0, stream, x, Wr1, br1, xr, NN);
  hipLaunchKernelGGL(k_gat, dim3((NN + 7) / 8), b256, 0, stream, xl, xr, offs, ssrc, att1, bias1, res, h1);
  hipLaunchKernelGGL(k_linmfma, ling, b256, 0, stream, h1, Wl2, bl2, xl, NN);
  hipLaunchKernelGGL(k_linmfma, ling, b256, 0, stream, h1, Wr2, br2, xr, NN);
  hipLaunchKernelGGL(k_gat, dim3((NN + 7) / 8), b256, 0, stream, xl, xr, offs, ssrc, att2, bias2, h1, h2);
  hipLaunchKernelGGL(k_pool, dim3((NN + 127) / 128), b256, 0, stream, h2, batch, pooled);
  hipLaunchKernelGGL(k_mlp, dim3(NB), dim3(128), 0, stream, pooled, batch, domain,
                     Wg, bg, Wd, bd, Wf1, bf1, Wf2, bf2, Wf3, bf3, outp);
}

// Round 4
// 322.999 us; speedup vs baseline: 1.8237x; 1.1393x over previous
//
#include <hip/hip_runtime.h>
#include <math.h>

#define NN 50000
#define NE 800000
#define FD 128      // IN == HC == 128
#define NB 64
#define DDIM 32
#define SCAN_BLK 1024
#define NSCAN ((NN + SCAN_BLK - 1) / SCAN_BLK)   // 49

typedef __attribute__((ext_vector_type(8))) short short8v;
typedef __attribute__((ext_vector_type(4))) float f32x4;

// ---------------- init: zero degree histogram + pooled accumulators ----------------
__global__ void k_init(int* __restrict__ deg, float* __restrict__ pooled) {
  int i = blockIdx.x * blockDim.x + threadIdx.x;
  if (i < NN) deg[i] = 0;
  if (i < NB * FD) pooled[i] = 0.f;
}

// ---------------- degree histogram over edge destinations ----------------
__global__ void k_hist(const int* __restrict__ dst, int* __restrict__ deg) {
  int e = blockIdx.x * blockDim.x + threadIdx.x;
  if (e < NE) atomicAdd(&deg[dst[e]], 1);
}

// ---------------- hierarchical scan ----------------
__global__ __launch_bounds__(SCAN_BLK) void k_scan1(const int* __restrict__ deg,
                                                    int* __restrict__ excl,
                                                    int* __restrict__ blocksum) {
  __shared__ int ws[16];
  int t = threadIdx.x;
  int i = blockIdx.x * SCAN_BLK + t;
  int v = (i < NN) ? deg[i] : 0;
  int lane = t & 63, wave = t >> 6;
  int s = v;
  #pragma unroll
  for (int off = 1; off < 64; off <<= 1) {
    int y = __shfl_up(s, off, 64);
    if (lane >= off) s += y;
  }
  if (lane == 63) ws[wave] = s;
  __syncthreads();
  if (t < 16) {
    int x = ws[t];
    #pragma unroll
    for (int off = 1; off < 16; off <<= 1) {
      int y = __shfl_up(x, off, 64);
      if (t >= off) x += y;
    }
    ws[t] = x;
  }
  __syncthreads();
  int incl = s + (wave > 0 ? ws[wave - 1] : 0);
  if (i < NN) excl[i] = incl - v;
  if (t == SCAN_BLK - 1) blocksum[blockIdx.x] = incl;
}

__global__ void k_scan2(int* __restrict__ blocksum) {
  int t = threadIdx.x;   // 64 threads
  int v = (t < NSCAN) ? blocksum[t] : 0;
  int s = v;
  #pragma unroll
  for (int off = 1; off < 64; off <<= 1) {
    int y = __shfl_up(s, off, 64);
    if (t >= off) s += y;
  }
  if (t < NSCAN) blocksum[t] = s - v;
  if (t == 63) blocksum[NSCAN] = s;
}

__global__ __launch_bounds__(SCAN_BLK) void k_scan3(const int* __restrict__ excl,
                                                    const int* __restrict__ blocksum,
                                                    int* __restrict__ offs,
                                                    int* __restrict__ cursor) {
  int t = threadIdx.x;
  int i = blockIdx.x * SCAN_BLK + t;
  if (i < NN) {
    int o = excl[i] + blocksum[blockIdx.x];
    offs[i] = o;
    cursor[i] = o;
  }
  if (i == 0) offs[NN] = blocksum[NSCAN];
}

// ---------------- scatter edge sources into CSR order ----------------
__global__ void k_scatter(const int* __restrict__ src, const int* __restrict__ dst,
                          int* __restrict__ cursor, int* __restrict__ ssrc) {
  int e = blockIdx.x * blockDim.x + threadIdx.x;
  if (e < NE) {
    int p = atomicAdd(&cursor[dst[e]], 1);
    ssrc[p] = src[e];
  }
}

// ---------------- bf16 helpers ----------------
__device__ __forceinline__ unsigned short f2bf(float f) {
  unsigned u = __float_as_uint(f);
  u += 0x7fffu + ((u >> 16) & 1);          // RNE
  return (unsigned short)(u >> 16);
}
__device__ __forceinline__ float bfh2f(unsigned short h) {
  return __uint_as_float(((unsigned)h) << 16);
}

// ---------------- MFMA linear: out[r][c] = sum_k in[r][k]*W[c][k] + b[c] ------------
// Block tile M=64 x N=128, K staged in two 64-halves. 4 waves (2x2), wave tile 32x64.
// bf16 hi/lo split, 3 MFMA per product group, fp32 accumulate. LDS 48 KB.
// out (fp32) and/or out_bf (packed bf16) may be null.
__global__ __launch_bounds__(256) void k_linmfma(const float* __restrict__ in,
    const float* __restrict__ W, const float* __restrict__ bias,
    float* __restrict__ out, unsigned short* __restrict__ out_bf, int nrows) {
  __shared__ unsigned short s_ah[64 * 64];   // 8 KB
  __shared__ unsigned short s_al[64 * 64];   // 8 KB
  __shared__ unsigned short s_wh[128 * 64];  // 16 KB
  __shared__ unsigned short s_wl[128 * 64];  // 16 KB
  const int tid = threadIdx.x;
  const int lane = tid & 63;
  const int wv = tid >> 6;
  const int wr = wv >> 1, wc = wv & 1;
  const int m0 = wr * 32, n0 = wc * 64;
  const int rbase = blockIdx.x * 64;
  const int g = lane >> 4;       // quarter-wave group (k-slice)
  const int lr = lane & 15;

  f32x4 acc[2][4];
  #pragma unroll
  for (int mt = 0; mt < 2; ++mt)
    #pragma unroll
    for (int nt = 0; nt < 4; ++nt)
      acc[mt][nt] = (f32x4){0.f, 0.f, 0.f, 0.f};

  float bv[4];
  #pragma unroll
  for (int nt = 0; nt < 4; ++nt) bv[nt] = bias[n0 + nt * 16 + lr];

  for (int kh = 0; kh < 2; ++kh) {
    if (kh) __syncthreads();   // previous compute done before restage
    // stage A half: 64 rows x 8 slots (8 bf16 per slot)
    #pragma unroll
    for (int it = 0; it < 2; ++it) {
      int c = it * 256 + tid;
      int row = c >> 3, slot = c & 7;
      int rg = rbase + row;
      float f[8];
      if (rg < nrows) {
        float4 a0 = *(const float4*)&in[(size_t)rg * 128 + kh * 64 + slot * 8];
        float4 a1 = *(const float4*)&in[(size_t)rg * 128 + kh * 64 + slot * 8 + 4];
        f[0] = a0.x; f[1] = a0.y; f[2] = a0.z; f[3] = a0.w;
        f[4] = a1.x; f[5] = a1.y; f[6] = a1.z; f[7] = a1.w;
      } else {
        #pragma unroll
        for (int j = 0; j < 8; ++j) f[j] = 0.f;
      }
      short8v hi, lo;
      #pragma unroll
      for (int j = 0; j < 8; ++j) {
        unsigned short h = f2bf(f[j]);
        hi[j] = (short)h;
        lo[j] = (short)f2bf(f[j] - bfh2f(h));
      }
      int idx = row * 64 + 8 * (slot ^ (row & 7));
      *(short8v*)&s_ah[idx] = hi;
      *(short8v*)&s_al[idx] = lo;
    }
    // stage W half: 128 rows (out cols) x 8 slots
    #pragma unroll
    for (int it = 0; it < 4; ++it) {
      int c = it * 256 + tid;
      int row = c >> 3, slot = c & 7;
      float4 a0 = *(const float4*)&W[(size_t)row * 128 + kh * 64 + slot * 8];
      float4 a1 = *(const float4*)&W[(size_t)row * 128 + kh * 64 + slot * 8 + 4];
      float f[8] = {a0.x, a0.y, a0.z, a0.w, a1.x, a1.y, a1.z, a1.w};
      short8v hi, lo;
      #pragma unroll
      for (int j = 0; j < 8; ++j) {
        unsigned short h = f2bf(f[j]);
        hi[j] = (short)h;
        lo[j] = (short)f2bf(f[j] - bfh2f(h));
      }
      int idx = row * 64 + 8 * (slot ^ (row & 7));
      *(short8v*)&s_wh[idx] = hi;
      *(short8v*)&s_wl[idx] = lo;
    }
    __syncthreads();
    #pragma unroll
    for (int ks = 0; ks < 2; ++ks) {
      short8v ah[2], al[2];
      #pragma unroll
      for (int mt = 0; mt < 2; ++mt) {
        int row = m0 + mt * 16 + lr;
        int idx = row * 64 + 8 * ((ks * 4 + g) ^ (row & 7));
        ah[mt] = *(const short8v*)&s_ah[idx];
        al[mt] = *(const short8v*)&s_al[idx];
      }
      #pragma unroll
      for (int nt = 0; nt < 4; ++nt) {
        int row = n0 + nt * 16 + lr;
        int idx = row * 64 + 8 * ((ks * 4 + g) ^ (row & 7));
        short8v bh = *(const short8v*)&s_wh[idx];
        short8v bl = *(const short8v*)&s_wl[idx];
        #pragma unroll
        for (int mt = 0; mt < 2; ++mt) {
          acc[mt][nt] = __builtin_amdgcn_mfma_f32_16x16x32_bf16(ah[mt], bh, acc[mt][nt], 0, 0, 0);
          acc[mt][nt] = __builtin_amdgcn_mfma_f32_16x16x32_bf16(ah[mt], bl, acc[mt][nt], 0, 0, 0);
          acc[mt][nt] = __builtin_amdgcn_mfma_f32_16x16x32_bf16(al[mt], bh, acc[mt][nt], 0, 0, 0);
        }
      }
    }
  }
  // store: D row = 4*g + i, col = lane&15 within each 16x16 tile
  #pragma unroll
  for (int mt = 0; mt < 2; ++mt)
    #pragma unroll
    for (int nt = 0; nt < 4; ++nt)
      #pragma unroll
      for (int i = 0; i < 4; ++i) {
        int r = rbase + m0 + mt * 16 + 4 * g + i;
        if (r < nrows) {
          float v = acc[mt][nt][i] + bv[nt];
          size_t o = (size_t)r * 128 + n0 + nt * 16 + lr;
          if (out) out[o] = v;
          if (out_bf) out_bf[o] = f2bf(v);
        }
      }
}

__device__ __forceinline__ float lrelu(float x) { return x > 0.f ? x : 0.2f * x; }

// ---------------- GATv2 edge+softmax+aggregate, bf16 gathers, online softmax ------------
// 32 lanes per node; 4-edge unroll for memory-level parallelism.
__global__ __launch_bounds__(256) void k_gat(const unsigned short* __restrict__ xl,
    const unsigned short* __restrict__ xr, const int* __restrict__ offs,
    const int* __restrict__ ssrc, const float* __restrict__ att,
    const float* __restrict__ bias, const float* __restrict__ resid,
    float* __restrict__ out) {
  int grp = threadIdx.x >> 5;
  int lane = threadIdx.x & 31;
  int n = blockIdx.x * 8 + grp;
  if (n >= NN) return;
  float4 att4 = ((const float4*)att)[lane];
  ushort4 xu = ((const ushort4*)xr)[(size_t)n * 32 + lane];
  float4 xr4 = make_float4(bfh2f(xu.x), bfh2f(xu.y), bfh2f(xu.z), bfh2f(xu.w));
  int e0 = offs[n], e1 = offs[n + 1];
  float m = -1e30f, den = 0.f;
  float4 acc = make_float4(0.f, 0.f, 0.f, 0.f);
  int e = e0;
  for (; e + 3 < e1; e += 4) {
    int s0 = ssrc[e], s1 = ssrc[e + 1], s2 = ssrc[e + 2], s3 = ssrc[e + 3];
    ushort4 u0 = ((const ushort4*)xl)[(size_t)s0 * 32 + lane];
    ushort4 u1 = ((const ushort4*)xl)[(size_t)s1 * 32 + lane];
    ushort4 u2 = ((const ushort4*)xl)[(size_t)s2 * 32 + lane];
    ushort4 u3 = ((const ushort4*)xl)[(size_t)s3 * 32 + lane];
    float4 v0 = make_float4(bfh2f(u0.x), bfh2f(u0.y), bfh2f(u0.z), bfh2f(u0.w));
    float4 v1 = make_float4(bfh2f(u1.x), bfh2f(u1.y), bfh2f(u1.z), bfh2f(u1.w));
    float4 v2 = make_float4(bfh2f(u2.x), bfh2f(u2.y), bfh2f(u2.z), bfh2f(u2.w));
    float4 v3 = make_float4(bfh2f(u3.x), bfh2f(u3.y), bfh2f(u3.z), bfh2f(u3.w));
    float p0 = lrelu(v0.x + xr4.x) * att4.x + lrelu(v0.y + xr4.y) * att4.y +
               lrelu(v0.z + xr4.z) * att4.z + lrelu(v0.w + xr4.w) * att4.w;
    float p1 = lrelu(v1.x + xr4.x) * att4.x + lrelu(v1.y + xr4.y) * att4.y +
               lrelu(v1.z + xr4.z) * att4.z + lrelu(v1.w + xr4.w) * att4.w;
    float p2 = lrelu(v2.x + xr4.x) * att4.x + lrelu(v2.y + xr4.y) * att4.y +
               lrelu(v2.z + xr4.z) * att4.z + lrelu(v2.w + xr4.w) * att4.w;
    float p3 = lrelu(v3.x + xr4.x) * att4.x + lrelu(v3.y + xr4.y) * att4.y +
               lrelu(v3.z + xr4.z) * att4.z + lrelu(v3.w + xr4.w) * att4.w;
    p0 += __shfl_xor(p0, 1, 64); p0 += __shfl_xor(p0, 2, 64); p0 += __shfl_xor(p0, 4, 64);
    p1 += __shfl_xor(p1, 1, 64); p1 += __shfl_xor(p1, 2, 64); p1 += __shfl_xor(p1, 4, 64);
    p2 += __shfl_xor(p2, 1, 64); p2 += __shfl_xor(p2, 2, 64); p2 += __shfl_xor(p2, 4, 64);
    p3 += __shfl_xor(p3, 1, 64); p3 += __shfl_xor(p3, 2, 64); p3 += __shfl_xor(p3, 4, 64);
    float nm = fmaxf(fmaxf(m, fmaxf(p0, p1)), fmaxf(p2, p3));
    float sc = __expf(m - nm);
    float w0 = __expf(p0 - nm), w1 = __expf(p1 - nm);
    float w2 = __expf(p2 - nm), w3 = __expf(p3 - nm);
    den = den * sc + w0 + w1 + w2 + w3;
    acc.x = acc.x * sc + w0 * v0.x + w1 * v1.x + w2 * v2.x + w3 * v3.x;
    acc.y = acc.y * sc + w0 * v0.y + w1 * v1.y + w2 * v2.y + w3 * v3.y;
    acc.z = acc.z * sc + w0 * v0.z + w1 * v1.z + w2 * v2.z + w3 * v3.z;
    acc.w = acc.w * sc + w0 * v0.w + w1 * v1.w + w2 * v2.w + w3 * v3.w;
    m = nm;
  }
  for (; e < e1; ++e) {
    int s0 = ssrc[e];
    ushort4 u0 = ((const ushort4*)xl)[(size_t)s0 * 32 + lane];
    float4 v0 = make_float4(bfh2f(u0.x), bfh2f(u0.y), bfh2f(u0.z), bfh2f(u0.w));
    float p0 = lrelu(v0.x + xr4.x) * att4.x + lrelu(v0.y + xr4.y) * att4.y +
               lrelu(v0.z + xr4.z) * att4.z + lrelu(v0.w + xr4.w) * att4.w;
    p0 += __shfl_xor(p0, 1, 64); p0 += __shfl_xor(p0, 2, 64); p0 += __shfl_xor(p0, 4, 64);
    float nm = fmaxf(m, p0);
    float sc = __expf(m - nm);
    float w0 = __expf(p0 - nm);
    den = den * sc + w0;
    acc.x = acc.x * sc + w0 * v0.x;
    acc.y = acc.y * sc + w0 * v0.y;
    acc.z = acc.z * sc + w0 * v0.z;
    acc.w = acc.w * sc + w0 * v0.w;
    m = nm;
  }
  float inv = (den > 0.f) ? 1.f / den : 0.f;
  float4 b4 = ((const float4*)bias)[lane];
  float4 r4 = ((const float4*)resid)[(size_t)n * 32 + lane];
  float4 o;
  o.x = fmaxf(acc.x * inv + b4.x, 0.f) + r4.x;
  o.y = fmaxf(acc.y * inv + b4.y, 0.f) + r4.y;
  o.z = fmaxf(acc.z * inv + b4.z, 0.f) + r4.z;
  o.w = fmaxf(acc.w * inv + b4.w, 0.f) + r4.w;
  ((float4*)out)[(size_t)n * 32 + lane] = o;
}

// ---------------- mean-pool over sorted batch, run-length-compressed atomics ----------------
__global__ __launch_bounds__(256) void k_pool(const float* __restrict__ h,
    const int* __restrict__ batch, float* __restrict__ pooled) {
  int col = threadIdx.x & 127;
  int ro = threadIdx.x >> 7;
  int n0 = blockIdx.x * 128;
  float rs = 0.f;
  int cb = -1;
  for (int i = ro; i < 128; i += 2) {
    int n = n0 + i;
    if (n >= NN) break;
    int bb = batch[n];
    if (bb != cb) {
      if (cb >= 0) atomicAdd(&pooled[cb * FD + col], rs);
      rs = 0.f; cb = bb;
    }
    rs += h[(size_t)n * FD + col];
  }
  if (cb >= 0) atomicAdd(&pooled[cb * FD + col], rs);
}

// ---------------- MLP head: one block per graph ----------------
__global__ __launch_bounds__(128) void k_mlp(const float* __restrict__ pooled,
    const int* __restrict__ batch, const float* __restrict__ domain,
    const float* __restrict__ Wg, const float* __restrict__ bg,
    const float* __restrict__ Wd, const float* __restrict__ bd,
    const float* __restrict__ Wf1, const float* __restrict__ bf1,
    const float* __restrict__ Wf2, const float* __restrict__ bf2,
    const float* __restrict__ Wf3, const float* __restrict__ bf3,
    float* __restrict__ out) {
  __shared__ float z[192];
  __shared__ float z1[128];
  __shared__ float z2[64];
  __shared__ float pm[128];
  __shared__ int cnt;
  int b = blockIdx.x, t = threadIdx.x;
  if (t == 0) {
    int lo = 0, hi = NN;
    while (lo < hi) { int mid = (lo + hi) >> 1; if (batch[mid] < b) lo = mid + 1; else hi = mid; }
    int lb = lo; lo = 0; hi = NN;
    while (lo < hi) { int mid = (lo + hi) >> 1; if (batch[mid] < b + 1) lo = mid + 1; else hi = mid; }
    cnt = lo - lb;
  }
  __syncthreads();
  float invc = 1.f / fmaxf((float)cnt, 1.f);
  pm[t] = pooled[b * FD + t] * invc;
  __syncthreads();
  {
    float a = bg[t];
    for (int k = 0; k < 128; ++k) a += pm[k] * Wg[t * 128 + k];
    z[t] = fmaxf(a, 0.f);
  }
  if (t < 64) {
    float a = bd[t];
    for (int k = 0; k < 32; ++k) a += domain[b * 32 + k] * Wd[t * 32 + k];
    z[128 + t] = fmaxf(a, 0.f);
  }
  __syncthreads();
  {
    float a = bf1[t];
    for (int k = 0; k < 192; ++k) a += z[k] * Wf1[t * 192 + k];
    z1[t] = fmaxf(a, 0.f);
  }
  __syncthreads();
  if (t < 64) {
    float a = bf2[t];
    for (int k = 0; k < 128; ++k) a += z1[k] * Wf2[t * 128 + k];
    z2[t] = fmaxf(a, 0.f);
  }
  __syncthreads();
  if (t < 64) {
    float v = z2[t] * Wf3[t];
    for (int off = 1; off < 64; off <<= 1) v += __shfl_xor(v, off, 64);
    if (t == 0) out[b] = v + bf3[0];
  }
}

extern "C" void kernel_launch(void* const* d_in, const int* in_sizes, int n_in,
                              void* d_out, int out_size, void* d_ws, size_t ws_size,
                              hipStream_t stream) {
  const float* x      = (const float*)d_in[0];
  const float* domain = (const float*)d_in[1];
  const float* Wl1 = (const float*)d_in[2];  const float* bl1 = (const float*)d_in[3];
  const float* Wr1 = (const float*)d_in[4];  const float* br1 = (const float*)d_in[5];
  const float* att1= (const float*)d_in[6];  const float* bias1=(const float*)d_in[7];
  const float* Wl2 = (const float*)d_in[8];  const float* bl2 = (const float*)d_in[9];
  const float* Wr2 = (const float*)d_in[10]; const float* br2 = (const float*)d_in[11];
  const float* att2= (const float*)d_in[12]; const float* bias2=(const float*)d_in[13];
  const float* Wres= (const float*)d_in[14]; const float* bres= (const float*)d_in[15];
  const float* Wd  = (const float*)d_in[16]; const float* bd  = (const float*)d_in[17];
  const float* Wg  = (const float*)d_in[18]; const float* bg  = (const float*)d_in[19];
  const float* Wf1 = (const float*)d_in[20]; const float* bf1 = (const float*)d_in[21];
  const float* Wf2 = (const float*)d_in[22]; const float* bf2 = (const float*)d_in[23];
  const float* Wf3 = (const float*)d_in[24]; const float* bf3 = (const float*)d_in[25];
  const int* ei    = (const int*)d_in[26];
  const int* batch = (const int*)d_in[27];
  const int* esrc = ei;
  const int* edst = ei + NE;
  float* outp = (float*)d_out;

  char* p = (char*)d_ws;
  auto carve = [&](size_t bytes) { char* r = p; p += (bytes + 255) & ~(size_t)255; return r; };
  int* deg      = (int*)carve((size_t)NN * 4);
  int* offs     = (int*)carve((size_t)(NN + 1) * 4);
  int* cursor   = (int*)carve((size_t)NN * 4);
  int* ssrc     = (int*)carve((size_t)NE * 4);
  int* excl     = (int*)carve((size_t)NN * 4);
  int* blocksum = (int*)carve((size_t)(NSCAN + 1) * 4);
  unsigned short* xl = (unsigned short*)carve((size_t)NN * FD * 2);
  unsigned short* xr = (unsigned short*)carve((size_t)NN * FD * 2);
  float* res    = (float*)carve((size_t)NN * FD * 4);
  float* h1     = (float*)carve((size_t)NN * FD * 4);
  float* pooled = (float*)carve((size_t)NB * FD * 4);
  float* h2 = res;   // res dead after first GAT; alias

  dim3 b256(256);
  hipLaunchKernelGGL(k_init, dim3((NN + 255) / 256), b256, 0, stream, deg, pooled);
  hipLaunchKernelGGL(k_hist, dim3((NE + 255) / 256), b256, 0, stream, edst, deg);
  hipLaunchKernelGGL(k_scan1, dim3(NSCAN), dim3(SCAN_BLK), 0, stream, deg, excl, blocksum);
  hipLaunchKernelGGL(k_scan2, dim3(1), dim3(64), 0, stream, blocksum);
  hipLaunchKernelGGL(k_scan3, dim3(NSCAN), dim3(SCAN_BLK), 0, stream, excl, blocksum, offs, cursor);
  hipLaunchKernelGGL(k_scatter, dim3((NE + 255) / 256), b256, 0, stream, esrc, edst, cursor, ssrc);

  dim3 ling((NN + 63) / 64);
  hipLaunchKernelGGL(k_linmfma, ling, b256, 0, stream, x, Wres, bres, res, (unsigned short*)nullptr, NN);
  hipLaunchKernelGGL(k_linmfma, ling, b256, 0, stream, x, Wl1, bl1, (float*)nullptr, xl, NN);
  hipLaunchKernelGGL(k_linmfma, ling, b256, 0, stream, x, Wr1, br1, (float*)nullptr, xr, NN);
  hipLaunchKernelGGL(k_gat, dim3((NN + 7) / 8), b256, 0, stream, xl, xr, offs, ssrc, att1, bias1, res, h1);
  hipLaunchKernelGGL(k_linmfma, ling, b256, 0, stream, h1, Wl2, bl2, (float*)nullptr, xl, NN);
  hipLaunchKernelGGL(k_linmfma, ling, b256, 0, stream, h1, Wr2, br2, (float*)nullptr, xr, NN);
  hipLaunchKernelGGL(k_gat, dim3((NN + 7) / 8), b256, 0, stream, xl, xr, offs, ssrc, att2, bias2, h1, h2);
  hipLaunchKernelGGL(k_pool, dim3((NN + 127) / 128), b256, 0, stream, h2, batch, pooled);
  hipLaunchKernelGGL(k_mlp, dim3(NB), dim3(128), 0, stream, pooled, batch, domain,
                     Wg, bg, Wd, bd, Wf1, bf1, Wf2, bf2, Wf3, bf3, outp);
}